// Round 1
// 690.195 us; speedup vs baseline: 1.0106x; 1.0106x over previous
//
#include <hip/hip_runtime.h>
#include <math.h>

#define N_ATOMS 50000
#define N_EDGES 1600000
#define NRBF 20
#define TILE_E 32
#define N_TILES (N_EDGES / TILE_E)   // 50000 exact

typedef __attribute__((ext_vector_type(8))) short bf16x8;
typedef __attribute__((ext_vector_type(4))) short s16x4;
typedef __attribute__((ext_vector_type(4))) float f32x4;

__device__ __forceinline__ float sp(float v) {    // softplus, NO -log2 shift
    const float a = fabsf(v);
    const float e = exp2f(a * -1.4426950408889634f);
    const float l = log2f(1.0f + e);
    return fmaxf(v, 0.0f) + l * 0.6931471805599453f;
}
__device__ __forceinline__ float ssp(float v) {   // shifted softplus
    return sp(v) - 0.6931471805599453f;
}
__device__ __forceinline__ unsigned short f2bf(float f) {   // fp32 -> bf16 bits, RNE
    unsigned int u = __float_as_uint(f);
    u += 0x7fff + ((u >> 16) & 1);
    return (unsigned short)(u >> 16);
}
__device__ __forceinline__ float bf2f(unsigned short b) {
    return __uint_as_float(((unsigned int)b) << 16);
}
// LDS-only barrier: drains lgkmcnt but NOT vmcnt, so register prefetches of
// global data survive across phases (all inter-wave traffic goes through LDS).
__device__ __forceinline__ void lds_barrier() {
    __asm__ __volatile__("s_waitcnt lgkmcnt(0)\ns_barrier" ::: "memory");
}

// ---------------------------------------------------------------------------
// Row-GEMM v2: A tile staged once per block through LDS (bf16 hi/lo planes),
// removing the 4x redundant per-wave A loads + conversions of v1. Next tile's
// A is prefetched into registers while the current tile's MFMAs run.
template<bool SSP_ACT, bool BIAS>
__global__ __launch_bounds__(512) void rowgemm2(
    const float* __restrict__ A, const float* __restrict__ W,
    const float* __restrict__ bias, float* __restrict__ C, int nrows)
{
    __shared__ short sAh[32][136];   // [32][136]: row stride 272B -> uniform-8
    __shared__ short sAl[32][136];   // bank load on ds_read_b128 (same as sTH)

    const int tid  = threadIdx.x;
    const int wave = tid >> 6, lane = tid & 63;
    const int l15  = lane & 15, quad = lane >> 4;
    const int rhalf = wave >> 2, cpair = wave & 3;
    const int r0 = rhalf * 16;
    const int ntiles = (nrows + 31) >> 5;
    const int stride = gridDim.x;

    // staging coords: 2 float4 per thread covers the 32x128 tile
    const int sr0 = tid >> 5;            // rows 0..15
    const int sr1 = sr0 + 16;            // rows 16..31
    const int sc0 = (tid & 31) * 4;      // col group

    // ---- W fragments (hi/lo) + bias, once per block ----
    bf16x8 wh[2][4], wl[2][4];
    float br[2];
    #pragma unroll
    for (int ct = 0; ct < 2; ++ct) {
        const int c = cpair * 32 + ct * 16 + l15;
        br[ct] = BIAS ? bias[c] : 0.0f;
        #pragma unroll
        for (int kk = 0; kk < 4; ++kk) {
            #pragma unroll
            for (int j = 0; j < 8; ++j) {
                const int k = kk * 32 + quad * 8 + j;
                const float v = W[k * 128 + c];
                const unsigned short hb = f2bf(v);
                wh[ct][kk][j] = (short)hb;
                wl[ct][kk][j] = (short)f2bf(v - bf2f(hb));
            }
        }
    }

    int t = blockIdx.x;
    if (t >= ntiles) return;

    float4 v0, v1;
    {
        const int ra = t * 32 + sr0, rb = t * 32 + sr1;
        v0 = *(const float4*)(A + (size_t)((ra < nrows) ? ra : nrows - 1) * 128 + sc0);
        v1 = *(const float4*)(A + (size_t)((rb < nrows) ? rb : nrows - 1) * 128 + sc0);
    }

    while (true) {
        // ---- stage tile t into LDS (convert to bf16 hi/lo) ----
        {
            const float fa[4] = {v0.x, v0.y, v0.z, v0.w};
            const float fb[4] = {v1.x, v1.y, v1.z, v1.w};
            s16x4 ha, la, hbv, lb;
            #pragma unroll
            for (int j = 0; j < 4; ++j) {
                const unsigned short h0 = f2bf(fa[j]);
                ha[j] = (short)h0; la[j] = (short)f2bf(fa[j] - bf2f(h0));
                const unsigned short h1 = f2bf(fb[j]);
                hbv[j] = (short)h1; lb[j] = (short)f2bf(fb[j] - bf2f(h1));
            }
            *(s16x4*)(&sAh[sr0][sc0]) = ha;  *(s16x4*)(&sAl[sr0][sc0]) = la;
            *(s16x4*)(&sAh[sr1][sc0]) = hbv; *(s16x4*)(&sAl[sr1][sc0]) = lb;
        }
        __syncthreads();

        const int tn = t + stride;
        const bool more = (tn < ntiles);
        float4 n0, n1;
        if (more) {   // prefetch next tile while MFMAs run
            const int ra = tn * 32 + sr0, rb = tn * 32 + sr1;
            n0 = *(const float4*)(A + (size_t)((ra < nrows) ? ra : nrows - 1) * 128 + sc0);
            n1 = *(const float4*)(A + (size_t)((rb < nrows) ? rb : nrows - 1) * 128 + sc0);
        }

        // ---- fragments from LDS, MFMA, epilogue ----
        bf16x8 ah[4], al[4];
        #pragma unroll
        for (int kk = 0; kk < 4; ++kk) {
            ah[kk] = *(const bf16x8*)(&sAh[r0 + l15][kk * 32 + quad * 8]);
            al[kk] = *(const bf16x8*)(&sAl[r0 + l15][kk * 32 + quad * 8]);
        }
        #pragma unroll
        for (int ct = 0; ct < 2; ++ct) {
            f32x4 acc = {0.0f, 0.0f, 0.0f, 0.0f};
            #pragma unroll
            for (int kk = 0; kk < 4; ++kk) {
                acc = __builtin_amdgcn_mfma_f32_16x16x32_bf16(ah[kk], wh[ct][kk], acc, 0, 0, 0);
                acc = __builtin_amdgcn_mfma_f32_16x16x32_bf16(al[kk], wh[ct][kk], acc, 0, 0, 0);
                acc = __builtin_amdgcn_mfma_f32_16x16x32_bf16(ah[kk], wl[ct][kk], acc, 0, 0, 0);
            }
            const int c = cpair * 32 + ct * 16 + l15;
            #pragma unroll
            for (int r = 0; r < 4; ++r) {
                const int row = t * 32 + r0 + quad * 4 + r;
                if (row < nrows) {
                    float v = acc[r] + br[ct];
                    if (SSP_ACT) v = ssp(v);
                    C[(size_t)row * 128 + c] = v;
                }
            }
        }
        if (!more) break;
        __syncthreads();          // frag reads done; LDS reusable
        v0 = n0; v1 = n1; t = tn;
    }
}

// ---------------------------------------------------------------------------
// Fused edge kernel. Changes vs v1: (1) h-gather addresses precomputed as
// 32-bit element offsets (j*128+c0) -> base+voffset loads, no v_mad_u64
// chains; (2) layer-1 activation is plain softplus, the -ln2 shift is folded
// exactly into b2r via -ln2*colsum(bf16(W2)); (3) grid 768 = 3 blocks/CU.
__global__ __launch_bounds__(512, 2) void edge_mfma(
    const float* __restrict__ f_ij, const float* __restrict__ rcut,
    const int* __restrict__ idx_i, const int* __restrict__ idx_j,
    const float* __restrict__ h,
    const float* __restrict__ W1, const float* __restrict__ b1,
    const float* __restrict__ W2, const float* __restrict__ b2,
    float* __restrict__ y)
{
    __shared__ unsigned short sTH[32][136];   // t tile, bf16-hi
    __shared__ float sXT[128][33];            // xij transposed, conflict-free b32

    const int tid  = threadIdx.x;
    const int wave = tid >> 6, lane = tid & 63;
    const int l15  = lane & 15, quad = lane >> 4;
    const int rhalf = wave >> 2, cpair = wave & 3;
    const int r0  = rhalf * 16;
    const int c0  = cpair * 32 + l15;
    const int rr  = r0 + quad * 4;
    const int col = tid & 127, qtr = tid >> 7;

    // ---- weight fragments (hi planes; f_ij keeps hi/lo via A operand) ----
    bf16x8 w1h[2];
    bf16x8 w2h[2][4];
    float b1r[2], b2r[2];
    #pragma unroll
    for (int ct = 0; ct < 2; ++ct) {
        const int c = c0 + ct * 16;
        b1r[ct] = b1[c];
        #pragma unroll
        for (int j = 0; j < 8; ++j) {
            const int k = quad * 8 + j;
            w1h[ct][j] = (short)f2bf((k < NRBF) ? W1[k * 128 + c] : 0.0f);
        }
        float csum = 0.0f;
        #pragma unroll
        for (int kk = 0; kk < 4; ++kk) {
            #pragma unroll
            for (int j = 0; j < 8; ++j) {
                const float wv = W2[(kk * 32 + quad * 8 + j) * 128 + c];
                const unsigned short hb = f2bf(wv);
                w2h[ct][kk][j] = (short)hb;
                csum += bf2f(hb);
            }
        }
        // colsum over all 128 k: reduce across the 4 quads holding this column
        csum += __shfl_xor(csum, 16);
        csum += __shfl_xor(csum, 32);
        b2r[ct] = b2[c] - 0.6931471805599453f * csum;   // folds ssp's -ln2
    }

    const int nb = gridDim.x;
    const int t0 = (int)(((long long)blockIdx.x * N_TILES) / nb);
    const int t1 = (int)(((long long)(blockIdx.x + 1) * N_TILES) / nb);
    if (t0 >= t1) return;

    int   curI = idx_i[(size_t)t0 * TILE_E];
    float accV = 0.0f;

    // ---- pipeline state (plain locals) ----
    float4 apa, apb;                 // f_ij fragment, tile t
    float  arc0, arc1, arc2, arc3;   // rcut, tile t
    float  ahn[2][4];                // h gather, tile t
    int    jn0, jn1, jn2v, jn3;      // h element offsets (j*128+c0), tile t+1

    // ---- preload tile t0 ----
    {
        const int e0 = t0 * TILE_E;
        const float* rp = f_ij + (size_t)(e0 + r0 + l15) * NRBF;
        float4 za = {0,0,0,0}, zb = {0,0,0,0};
        if (quad < 2)       { za = *(const float4*)(rp + quad * 8); zb = *(const float4*)(rp + quad * 8 + 4); }
        else if (quad == 2) { za = *(const float4*)(rp + 16); }
        apa = za; apb = zb;
        const float4 rq = *(const float4*)(rcut + e0 + rr);
        arc0 = rq.x; arc1 = rq.y; arc2 = rq.z; arc3 = rq.w;
        const int4 j0 = *(const int4*)(idx_j + e0 + rr);
        const int o0 = j0.x * 128 + c0, o1 = j0.y * 128 + c0;
        const int o2 = j0.z * 128 + c0, o3 = j0.w * 128 + c0;
        ahn[0][0] = h[o0]; ahn[0][1] = h[o1]; ahn[0][2] = h[o2]; ahn[0][3] = h[o3];
        ahn[1][0] = h[o0 + 16]; ahn[1][1] = h[o1 + 16];
        ahn[1][2] = h[o2 + 16]; ahn[1][3] = h[o3 + 16];
        const int tn = (t0 + 1 < N_TILES) ? t0 + 1 : N_TILES - 1;
        const int4 j1 = *(const int4*)(idx_j + tn * TILE_E + rr);
        jn0 = j1.x * 128 + c0; jn1 = j1.y * 128 + c0;
        jn2v = j1.z * 128 + c0; jn3 = j1.w * 128 + c0;
    }

    for (int t = t0; t < t1; ++t) {
        const int e0 = t * TILE_E;
        const int ta = (t + 1 < N_TILES) ? t + 1 : N_TILES - 1;
        const int tb = (t + 2 < N_TILES) ? t + 2 : N_TILES - 1;

        // ================= prefetch issue (top of iteration) =================
        int ii[8];
        {
            const int4 i0 = *(const int4*)(idx_i + e0 + qtr * 8);
            const int4 i1 = *(const int4*)(idx_i + e0 + qtr * 8 + 4);
            ii[0] = i0.x; ii[1] = i0.y; ii[2] = i0.z; ii[3] = i0.w;
            ii[4] = i1.x; ii[5] = i1.y; ii[6] = i1.z; ii[7] = i1.w;
        }
        float4 npa = {0,0,0,0}, npb = {0,0,0,0};
        {
            const float* rp = f_ij + (size_t)(ta * TILE_E + r0 + l15) * NRBF;
            if (quad < 2)       { npa = *(const float4*)(rp + quad * 8); npb = *(const float4*)(rp + quad * 8 + 4); }
            else if (quad == 2) { npa = *(const float4*)(rp + 16); }
        }
        float nrc0, nrc1, nrc2, nrc3;
        {
            const float4 rq = *(const float4*)(rcut + ta * TILE_E + rr);
            nrc0 = rq.x; nrc1 = rq.y; nrc2 = rq.z; nrc3 = rq.w;
        }
        int j20, j21, j22, j23;
        {
            const int4 jq = *(const int4*)(idx_j + tb * TILE_E + rr);
            j20 = jq.x * 128 + c0; j21 = jq.y * 128 + c0;
            j22 = jq.z * 128 + c0; j23 = jq.w * 128 + c0;
        }
        float nhn[2][4];   // h gather for tile t+1 (offsets computed last iter)
        nhn[0][0] = h[jn0]; nhn[0][1] = h[jn1]; nhn[0][2] = h[jn2v]; nhn[0][3] = h[jn3];
        nhn[1][0] = h[jn0 + 16]; nhn[1][1] = h[jn1 + 16];
        nhn[1][2] = h[jn2v + 16]; nhn[1][3] = h[jn3 + 16];

        // ================= layer 1: t = softplus(f_ij @ W1 + b1) =================
        {
            const float va[8] = {apa.x, apa.y, apa.z, apa.w, apb.x, apb.y, apb.z, apb.w};
            bf16x8 ah, al;
            #pragma unroll
            for (int j = 0; j < 8; ++j) {
                const unsigned short hb = f2bf(va[j]);
                ah[j] = (short)hb;
                al[j] = (short)f2bf(va[j] - bf2f(hb));
            }
            #pragma unroll
            for (int ct = 0; ct < 2; ++ct) {
                f32x4 d = {0.0f, 0.0f, 0.0f, 0.0f};
                d = __builtin_amdgcn_mfma_f32_16x16x32_bf16(ah, w1h[ct], d, 0, 0, 0);
                d = __builtin_amdgcn_mfma_f32_16x16x32_bf16(al, w1h[ct], d, 0, 0, 0);
                const int c = c0 + ct * 16;
                #pragma unroll
                for (int r = 0; r < 4; ++r)
                    sTH[rr + r][c] = f2bf(sp(d[r] + b1r[ct]));
            }
        }
        lds_barrier();   // B1: sTH visible; sXT free (prev reads done pre-B1)

        // ================= layer 2: xij -> sXT =================
        {
            bf16x8 ath[4];
            #pragma unroll
            for (int kk = 0; kk < 4; ++kk)
                ath[kk] = *(const bf16x8*)(&sTH[r0 + l15][kk * 32 + quad * 8]);
            const float arcv[4] = {arc0, arc1, arc2, arc3};
            #pragma unroll
            for (int ct = 0; ct < 2; ++ct) {
                f32x4 acc = {0.0f, 0.0f, 0.0f, 0.0f};
                #pragma unroll
                for (int kk = 0; kk < 4; ++kk)
                    acc = __builtin_amdgcn_mfma_f32_16x16x32_bf16(ath[kk], w2h[ct][kk], acc, 0, 0, 0);
                const int c = c0 + ct * 16;
                #pragma unroll
                for (int r = 0; r < 4; ++r) {
                    const float wij = (acc[r] + b2r[ct]) * arcv[r];
                    sXT[c][rr + r] = wij * ahn[ct][r];
                }
            }
        }
        lds_barrier();   // B2: sXT visible; sTH free for next tile

        // ================= segmented reduce (sorted idx_i) =================
        #pragma unroll
        for (int r = 0; r < 8; ++r) {
            const float v = sXT[col][qtr * 8 + r];
            const int i = ii[r];
            if (i != curI) {
                atomicAdd(&y[curI * 128 + col], accV);
                curI = i; accV = v;
            } else accV += v;
        }

        // ================= rotate pipeline state =================
        apa = npa; apb = npb;
        arc0 = nrc0; arc1 = nrc1; arc2 = nrc2; arc3 = nrc3;
        #pragma unroll
        for (int ct = 0; ct < 2; ++ct)
            #pragma unroll
            for (int r = 0; r < 4; ++r) ahn[ct][r] = nhn[ct][r];
        jn0 = j20; jn1 = j21; jn2v = j22; jn3 = j23;
    }
    atomicAdd(&y[curI * 128 + col], accV);
}

// ---------------------------------------------------------------------------
extern "C" void kernel_launch(void* const* d_in, const int* in_sizes, int n_in,
                              void* d_out, int out_size, void* d_ws, size_t ws_size,
                              hipStream_t stream) {
    const float* x      = (const float*)d_in[0];
    const float* f_ij   = (const float*)d_in[1];
    const float* rcut   = (const float*)d_in[2];
    const int*   idx_i  = (const int*)d_in[3];
    const int*   idx_j  = (const int*)d_in[4];
    const float* W_in2f = (const float*)d_in[5];
    const float* W_f1   = (const float*)d_in[6];
    const float* b_f1   = (const float*)d_in[7];
    const float* W_f2   = (const float*)d_in[8];
    const float* b_f2   = (const float*)d_in[9];
    const float* W_o1   = (const float*)d_in[10];
    const float* b_o1   = (const float*)d_in[11];
    const float* W_o2   = (const float*)d_in[12];
    const float* b_o2   = (const float*)d_in[13];

    float* out = (float*)d_out;
    float* h   = (float*)d_ws;   // 25.6 MB; reused as z after cfconv

    hipMemsetAsync(out, 0, (size_t)N_ATOMS * 128 * sizeof(float), stream);

    rowgemm2<false, false><<<512, 512, 0, stream>>>(x, W_in2f, nullptr, h, N_ATOMS);
    edge_mfma<<<768, 512, 0, stream>>>(f_ij, rcut, idx_i, idx_j, h,
                                       W_f1, b_f1, W_f2, b_f2, out);
    rowgemm2<true, true><<<512, 512, 0, stream>>>(out, W_o1, b_o1, h, N_ATOMS);
    rowgemm2<false, true><<<512, 512, 0, stream>>>(h, W_o2, b_o2, out, N_ATOMS);
}